// Round 7
// baseline (260.737 us; speedup 1.0000x reference)
//
#include <hip/hip_runtime.h>
#include <hip/hip_bf16.h>

#define B_  2
#define S_  2048
#define H_  24
#define DH_ 32
#define E_  768
#define SW_ (S_/32)   // mask words per row = 64

#define NB_QKV  ((S_/64)*(B_*H_))      // 1536 blocks (qkv part, dispatched first)
#define NB_MSK4 ((B_*S_*S_)/1024)      // 8192 blocks (4 rows x 64 keys per wave)
#define NB_WO   ((E_*E_)/1024)         // 576 blocks

typedef __attribute__((ext_vector_type(8))) short short8;   // 8 x bf16 bits
typedef __attribute__((ext_vector_type(4))) float f32x4;
typedef _Float16 half8  __attribute__((ext_vector_type(8)));
typedef _Float16 half2v __attribute__((ext_vector_type(2)));
typedef __fp16   fp16x2 __attribute__((ext_vector_type(2)));   // cvt_pkrtz return type

// fp32 pair -> packed fp16 (one v_cvt_pkrtz_f16_f32), as _Float16 vector
static __device__ __forceinline__ half2v cvt2h(float a, float b) {
    fp16x2 t = __builtin_amdgcn_cvt_pkrtz(a, b);
    return __builtin_bit_cast(half2v, t);
}

// 4 floats -> 4 bf16 packed in 8B
static __device__ __forceinline__ short4 pack4(float a, float b, float c, float d) {
    union { __hip_bfloat162 h[2]; short4 s; } u;
    u.h[0] = __float22bfloat162_rn(make_float2(a, b));
    u.h[1] = __float22bfloat162_rn(make_float2(c, d));
    return u.s;
}
static __device__ __forceinline__ short8 pack8f(const float* a, const float* b) {
    union { __hip_bfloat162 h[4]; short8 s; } u;
    u.h[0] = __float22bfloat162_rn(make_float2(a[0], a[1]));
    u.h[1] = __float22bfloat162_rn(make_float2(a[2], a[3]));
    u.h[2] = __float22bfloat162_rn(make_float2(b[0], b[1]));
    u.h[3] = __float22bfloat162_rn(make_float2(b[2], b[3]));
    return u.s;
}
static __device__ __forceinline__ short8 pack8(float4 a, float4 b) {
    union { __hip_bfloat162 h[4]; short8 s; } u;
    u.h[0] = __float22bfloat162_rn(make_float2(a.x, a.y));
    u.h[1] = __float22bfloat162_rn(make_float2(a.z, a.w));
    u.h[2] = __float22bfloat162_rn(make_float2(b.x, b.y));
    u.h[3] = __float22bfloat162_rn(make_float2(b.z, b.w));
    return u.s;
}
// weight fragment straight from fp32 W[h-base][d][e]: F[j] = W[(quad*8+j)*32+eo]
static __device__ __forceinline__ short8 wfrag(const float* __restrict__ Wb,
                                               int quad, int eo) {
    float w[8];
#pragma unroll
    for (int j = 0; j < 8; ++j) w[j] = Wb[(quad * 8 + j) * 32 + eo];
    return pack8f(w, w + 4);
}

// Q pre-scaled by (1/sqrt(32))*log2(e): MFMA scores land in the exp2 domain.
// Mask zeroes x (bitwise AND with sbfe sign-mask) BEFORE exp2; exp2(0) = 1.0
// exactly = exp(-1e-6) at working precision.
#define QSCALE  0.25503487f

// masked-exp2 on one f32 score: m = sext(bit) (0 or -1), x &= m, p = 2^x
static __device__ __forceinline__ float mexp2(float s, unsigned mw, int pos) {
    const int m = __builtin_amdgcn_sbfe((int)mw, pos, 1);     // 0 or 0xFFFFFFFF
    const int xi = __builtin_bit_cast(int, s) & m;
    return __builtin_amdgcn_exp2f(__builtin_bit_cast(float, xi));
}

// ---------------------------------------------------------------------------
// Kernel 0: FUSED prep + qkv (mutually independent parts, one launch).
// Mask part: 4 rows x 64 keys per wave, loads batched before ballots (R4).
// ---------------------------------------------------------------------------
__global__ __launch_bounds__(256) void prep_qkv_kernel(
    const float* __restrict__ x, const int* __restrict__ mask,
    const float* __restrict__ Wo,
    const float* __restrict__ Wq, const float* __restrict__ Wk,
    const float* __restrict__ Wv,
    __hip_bfloat16* __restrict__ Qo,
    __hip_bfloat16* __restrict__ Ko,      // permuted-key layout, bf16
    _Float16* __restrict__ Vto,           // fp16 (PV runs on f16 MFMA)
    unsigned int* __restrict__ mbits, _Float16* __restrict__ Wob)
{
    const int bx = blockIdx.x;
    if (bx < NB_QKV) {
        // ---- QKV: 16 s-rows/wave, 6 MFMAs. K stored PERMUTED within each
        // 32-key tile: key k=8q+4u+i -> slot (u<<4)|(q*4+i) so attn's score
        // MFMAs produce P directly in PV B-operand register layout. ----
        const int bh   = bx >> 5;            // [0,48)
        const int b    = bh / H_;
        const int h    = bh - b * H_;
        const int wave = threadIdx.x >> 6;
        const int lane = threadIdx.x & 63;
        const int col  = lane & 15;
        const int quad = lane >> 4;
        const int sw   = (bx & 31) * 64 + wave * 16;
        const int s    = sw + col;

        const float* xp = x + ((size_t)b * S_ + s) * E_ + h * DH_ + quad * 8;
        const float4 xa = *reinterpret_cast<const float4*>(xp);
        const float4 xb = *reinterpret_cast<const float4*>(xp + 4);
        const short8 xf = pack8(xa, xb);

        const int wb = h * DH_ * DH_;
        const short8 aQ0 = wfrag(Wq + wb, quad, col);
        const short8 aQ1 = wfrag(Wq + wb, quad, col + 16);
        const short8 aK0 = wfrag(Wk + wb, quad, col);
        const short8 aK1 = wfrag(Wk + wb, quad, col + 16);
        const short8 bV0 = wfrag(Wv + wb, quad, col);
        const short8 bV1 = wfrag(Wv + wb, quad, col + 16);

        const f32x4 z = {0.f, 0.f, 0.f, 0.f};
        const f32x4 qt0 = __builtin_amdgcn_mfma_f32_16x16x32_bf16(aQ0, xf, z, 0, 0, 0);
        const f32x4 qt1 = __builtin_amdgcn_mfma_f32_16x16x32_bf16(aQ1, xf, z, 0, 0, 0);
        const f32x4 kt0 = __builtin_amdgcn_mfma_f32_16x16x32_bf16(aK0, xf, z, 0, 0, 0);
        const f32x4 kt1 = __builtin_amdgcn_mfma_f32_16x16x32_bf16(aK1, xf, z, 0, 0, 0);
        const f32x4 vv0 = __builtin_amdgcn_mfma_f32_16x16x32_bf16(xf, bV0, z, 0, 0, 0);
        const f32x4 vv1 = __builtin_amdgcn_mfma_f32_16x16x32_bf16(xf, bV1, z, 0, 0, 0);

        __hip_bfloat16* qrow = Qo + ((size_t)bh * S_ + s) * DH_;
        *reinterpret_cast<short4*>(qrow + quad * 4) =
            pack4(qt0[0] * QSCALE, qt0[1] * QSCALE, qt0[2] * QSCALE, qt0[3] * QSCALE);
        *reinterpret_cast<short4*>(qrow + 16 + quad * 4) =
            pack4(qt1[0] * QSCALE, qt1[1] * QSCALE, qt1[2] * QSCALE, qt1[3] * QSCALE);

        const int t32  = s & 31;
        const int slot = (s & ~31) | (((t32 >> 2) & 1) << 4)
                       | (((t32 >> 3) << 2) | (t32 & 3));
        __hip_bfloat16* krow = Ko + ((size_t)bh * S_ + slot) * DH_;
        *reinterpret_cast<short4*>(krow + quad * 4)      = pack4(kt0[0], kt0[1], kt0[2], kt0[3]);
        *reinterpret_cast<short4*>(krow + 16 + quad * 4) = pack4(kt1[0], kt1[1], kt1[2], kt1[3]);

        const int sb = sw + quad * 4;
        union { half2v h[2]; uint2 u; } v0u, v1u;
        v0u.h[0] = cvt2h(vv0[0], vv0[1]); v0u.h[1] = cvt2h(vv0[2], vv0[3]);
        v1u.h[0] = cvt2h(vv1[0], vv1[1]); v1u.h[1] = cvt2h(vv1[2], vv1[3]);
        *reinterpret_cast<uint2*>(Vto + ((size_t)bh * DH_ + col) * S_ + sb)      = v0u.u;
        *reinterpret_cast<uint2*>(Vto + ((size_t)bh * DH_ + 16 + col) * S_ + sb) = v1u.u;
    } else if (bx < NB_QKV + NB_MSK4) {
        // 4 rows x 64 keys per wave; loads batched before ballots
        const int wid  = (bx - NB_QKV) * 4 + (threadIdx.x >> 6);  // [0, 32768)
        const int lane = threadIdx.x & 63;
        const int rg   = wid >> 5;          // row group of 4, [0, 1024)
        const int kc   = wid & 31;          // 64-key chunk, [0, 32)
        const int row0 = rg * 4;            // global row index (b*S + q)
        const int k    = kc * 64 + lane;
        int mv[4];
#pragma unroll
        for (int j = 0; j < 4; ++j)
            mv[j] = mask[(size_t)(row0 + j) * S_ + k];
#pragma unroll
        for (int j = 0; j < 4; ++j) {
            const unsigned long long bal = __ballot(mv[j] != 0);
            if (lane == 0) {
                uint2 w;
                w.x = (unsigned int)(bal & 0xffffffffull);
                w.y = (unsigned int)(bal >> 32);
                *reinterpret_cast<uint2*>(
                    mbits + (size_t)(row0 + j) * SW_ + kc * 2) = w;
            }
        }
    } else {
        const int i = ((bx - NB_QKV - NB_MSK4) * 256 + threadIdx.x) * 4;
        const float4 w = *reinterpret_cast<const float4*>(Wo + i);
        union { half2v h[2]; uint2 u; } uu;
        uu.h[0] = cvt2h(w.x, w.y);
        uu.h[1] = cvt2h(w.z, w.w);
        *reinterpret_cast<uint2*>(Wob + i) = uu.u;
    }
}

// ---------------------------------------------------------------------------
// Kernel 2: fused attention. R7: V joins the depth-1 register double-buffer
// (K+mask were pipelined in R3; V was still issued-and-consumed in-phase with
// only ~150 cycles of cover vs ~250-cycle L2 latency) + s_setprio(1) around
// MFMA bursts (m191 case: independent single-wave blocks at different phases
// on one SIMD). VGPR ~84 -> ~116, still under the 170 cap at 3 waves/SIMD.
// parts=2, grid = 1536*parts, block = 64.
// ---------------------------------------------------------------------------
__global__ __launch_bounds__(64, 3) void attn_kernel(
    const __hip_bfloat16* __restrict__ Q,     // [B*H][S][DH] (pre-scaled)
    const __hip_bfloat16* __restrict__ K,     // [B*H][S][DH] permuted tiles
    const _Float16* __restrict__ Vt,          // [B*H][DH][S] fp16
    const unsigned int* __restrict__ mbits,   // [B][S][S/32]
    _Float16* __restrict__ Opart,             // [parts][B][S][E] unnormalized
    float* __restrict__ lpart,                // [parts][B*H][S]
    int parts)
{
    const int bid  = blockIdx.x;
    const int xcd  = bid & 7;
    const int t_   = bid >> 3;                 // [0, 6*32*parts)
    const int bh   = xcd * 6 + (t_ % 6);
    const int rest = t_ / 6;                   // [0, 32*parts)
    const int qsub = rest & 31;
    const int part = rest >> 5;

    const int b    = bh / H_;
    const int h    = bh - b * H_;
    const int niter = S_ / (64 * parts);       // 16 (parts=2) — even
    const int kbeg  = part * (S_ / parts);
    const int lane = threadIdx.x & 63;
    const int col  = lane & 15;
    const int quad = lane >> 4;
    const int q0   = qsub * 64;

    const __hip_bfloat16* Qbh = Q  + (size_t)bh * S_ * DH_;
    const __hip_bfloat16* Kbh = K  + (size_t)bh * S_ * DH_;
    const _Float16*       Vbh = Vt + (size_t)bh * DH_ * S_;

    short8 qf[4];
#pragma unroll
    for (int t = 0; t < 4; ++t)
        qf[t] = *reinterpret_cast<const short8*>(
            Qbh + (size_t)(q0 + t * 16 + col) * DH_ + quad * 8);

    // prefetch cursors (advance one tile ahead of compute)
    const _Float16* Vp0 = Vbh + (size_t)col * S_ + kbeg + quad * 8;
    const _Float16* Vp1 = Vbh + (size_t)(16 + col) * S_ + kbeg + quad * 8;
    const __hip_bfloat16* Kf = Kbh + (size_t)(kbeg + col) * DH_ + quad * 8;
    const unsigned int* mbb = mbits + (size_t)b * S_ * SW_ + (kbeg >> 5);
    const unsigned int* mf0 = mbb + (size_t)(q0 +  0 + col) * SW_;
    const unsigned int* mf1 = mbb + (size_t)(q0 + 16 + col) * SW_;
    const unsigned int* mf2 = mbb + (size_t)(q0 + 32 + col) * SW_;
    const unsigned int* mf3 = mbb + (size_t)(q0 + 48 + col) * SW_;

    // sbfe bit positions: low-half keys at quad*8+r, high-half at quad*8+4+r
    const int posL = quad * 8;
    const int posH = quad * 8 + 4;

    union { uint4 u; half8 v; } onesu;
    onesu.u = make_uint4(0x3C003C00u, 0x3C003C00u, 0x3C003C00u, 0x3C003C00u);
    const half8 ones_h = onesu.v;

    f32x4 o0a[4], o1a[4], la[4];
#pragma unroll
    for (int t = 0; t < 4; ++t) {
        o0a[t] = (f32x4){0.f,0.f,0.f,0.f};
        o1a[t] = (f32x4){0.f,0.f,0.f,0.f};
        la[t]  = (f32x4){0.f,0.f,0.f,0.f};
    }

    // double-buffered K-fragments + mask words + V-fragments
    short8 ak0, ak1, ak2, ak3; uint2 am0, am1, am2, am3;
    half8  av0, av1, av2, av3;
    short8 bk0, bk1, bk2, bk3; uint2 bm0, bm1, bm2, bm3;
    half8  bv0, bv1, bv2, bv3;

    auto load_a = [&]() {
        ak0 = *reinterpret_cast<const short8*>(Kf);
        ak1 = *reinterpret_cast<const short8*>(Kf + 16 * DH_);
        ak2 = *reinterpret_cast<const short8*>(Kf + 32 * DH_);
        ak3 = *reinterpret_cast<const short8*>(Kf + 48 * DH_);
        av0 = *reinterpret_cast<const half8*>(Vp0);
        av1 = *reinterpret_cast<const half8*>(Vp1);
        av2 = *reinterpret_cast<const half8*>(Vp0 + 32);
        av3 = *reinterpret_cast<const half8*>(Vp1 + 32);
        am0 = *reinterpret_cast<const uint2*>(mf0);
        am1 = *reinterpret_cast<const uint2*>(mf1);
        am2 = *reinterpret_cast<const uint2*>(mf2);
        am3 = *reinterpret_cast<const uint2*>(mf3);
        Kf += 64 * DH_; Vp0 += 64; Vp1 += 64;
        mf0 += 2; mf1 += 2; mf2 += 2; mf3 += 2;
    };
    auto load_b = [&]() {
        bk0 = *reinterpret_cast<const short8*>(Kf);
        bk1 = *reinterpret_cast<const short8*>(Kf + 16 * DH_);
        bk2 = *reinterpret_cast<const short8*>(Kf + 32 * DH_);
        bk3 = *reinterpret_cast<const short8*>(Kf + 48 * DH_);
        bv0 = *reinterpret_cast<const half8*>(Vp0);
        bv1 = *reinterpret_cast<const half8*>(Vp1);
        bv2 = *reinterpret_cast<const half8*>(Vp0 + 32);
        bv3 = *reinterpret_cast<const half8*>(Vp1 + 32);
        bm0 = *reinterpret_cast<const uint2*>(mf0);
        bm1 = *reinterpret_cast<const uint2*>(mf1);
        bm2 = *reinterpret_cast<const uint2*>(mf2);
        bm3 = *reinterpret_cast<const uint2*>(mf3);
        Kf += 64 * DH_; Vp0 += 64; Vp1 += 64;
        mf0 += 2; mf1 += 2; mf2 += 2; mf3 += 2;
    };

    auto compute = [&](const short8& kA0, const short8& kA1,
                       const short8& kB0, const short8& kB1,
                       const half8& vA0, const half8& vA1,
                       const half8& vB0, const half8& vB1,
                       uint2 w0, uint2 w1, uint2 w2, uint2 w3) {
        const uint2 mw[4] = {w0, w1, w2, w3};
        const f32x4 z = {0.f, 0.f, 0.f, 0.f};

        // ---- subtile A (keys +0..31) ----
        f32x4 s0[4], s1[4];
        __builtin_amdgcn_s_setprio(1);
#pragma unroll
        for (int t = 0; t < 4; ++t) {
            s0[t] = __builtin_amdgcn_mfma_f32_16x16x32_bf16(kA0, qf[t], z, 0, 0, 0);
            s1[t] = __builtin_amdgcn_mfma_f32_16x16x32_bf16(kA1, qf[t], z, 0, 0, 0);
        }
        __builtin_amdgcn_s_setprio(0);
#pragma unroll
        for (int t = 0; t < 4; ++t) {
            float p0[4], p1[4];
#pragma unroll
            for (int r = 0; r < 4; ++r) {
                p0[r] = mexp2(s0[t][r], mw[t].x, posL + r);
                p1[r] = mexp2(s1[t][r], mw[t].x, posH + r);
            }
            union { half2v h[4]; half8 v; } pu;
            pu.h[0] = cvt2h(p0[0], p0[1]);
            pu.h[1] = cvt2h(p0[2], p0[3]);
            pu.h[2] = cvt2h(p1[0], p1[1]);
            pu.h[3] = cvt2h(p1[2], p1[3]);
            const half8 pf = pu.v;
            __builtin_amdgcn_s_setprio(1);
            o0a[t] = __builtin_amdgcn_mfma_f32_16x16x32_f16(vA0, pf, o0a[t], 0, 0, 0);
            o1a[t] = __builtin_amdgcn_mfma_f32_16x16x32_f16(vA1, pf, o1a[t], 0, 0, 0);
            la[t]  = __builtin_amdgcn_mfma_f32_16x16x32_f16(ones_h, pf, la[t], 0, 0, 0);
            __builtin_amdgcn_s_setprio(0);
        }

        // ---- subtile B (keys +32..63) ----
        __builtin_amdgcn_s_setprio(1);
#pragma unroll
        for (int t = 0; t < 4; ++t) {
            s0[t] = __builtin_amdgcn_mfma_f32_16x16x32_bf16(kB0, qf[t], z, 0, 0, 0);
            s1[t] = __builtin_amdgcn_mfma_f32_16x16x32_bf16(kB1, qf[t], z, 0, 0, 0);
        }
        __builtin_amdgcn_s_setprio(0);
#pragma unroll
        for (int t = 0; t < 4; ++t) {
            float p0[4], p1[4];
#pragma unroll
            for (int r = 0; r < 4; ++r) {
                p0[r] = mexp2(s0[t][r], mw[t].y, posL + r);
                p1[r] = mexp2(s1[t][r], mw[t].y, posH + r);
            }
            union { half2v h[4]; half8 v; } pu;
            pu.h[0] = cvt2h(p0[0], p0[1]);
            pu.h[1] = cvt2h(p0[2], p0[3]);
            pu.h[2] = cvt2h(p1[0], p1[1]);
            pu.h[3] = cvt2h(p1[2], p1[3]);
            const half8 pf = pu.v;
            __builtin_amdgcn_s_setprio(1);
            o0a[t] = __builtin_amdgcn_mfma_f32_16x16x32_f16(vB0, pf, o0a[t], 0, 0, 0);
            o1a[t] = __builtin_amdgcn_mfma_f32_16x16x32_f16(vB1, pf, o1a[t], 0, 0, 0);
            la[t]  = __builtin_amdgcn_mfma_f32_16x16x32_f16(ones_h, pf, la[t], 0, 0, 0);
            __builtin_amdgcn_s_setprio(0);
        }
    };

    // software pipeline: prefetch depth 1 (K, V, mask), 2x-unrolled rotation
    load_a();
    for (int it = 0; it < niter; it += 2) {
        load_b();                                    // tile it+1
        compute(ak0, ak1, ak2, ak3, av0, av1, av2, av3, am0, am1, am2, am3);
        load_a();                                    // tile it+2 (overrun on last pair: unused)
        compute(bk0, bk1, bk2, bk3, bv0, bv1, bv2, bv3, bm0, bm1, bm2, bm3);
    }

    _Float16* Ob = Opart + (size_t)part * B_ * S_ * E_;
    float* lp = lpart + (size_t)part * B_ * H_ * S_ + (size_t)bh * S_;
#pragma unroll
    for (int t = 0; t < 4; ++t) {
        union { half2v h[2]; uint2 u; } u0, u1;
        u0.h[0] = cvt2h(o0a[t][0], o0a[t][1]);
        u0.h[1] = cvt2h(o0a[t][2], o0a[t][3]);
        u1.h[0] = cvt2h(o1a[t][0], o1a[t][1]);
        u1.h[1] = cvt2h(o1a[t][2], o1a[t][3]);
        _Float16* orow = Ob + ((size_t)b * S_ + q0 + t * 16 + col) * E_ + h * DH_;
        *reinterpret_cast<uint2*>(orow + quad * 4)      = u0.u;
        *reinterpret_cast<uint2*>(orow + 16 + quad * 4) = u1.u;
        if (quad == 0) lp[q0 + t * 16 + col] = la[t][0];
    }
}

// ---------------------------------------------------------------------------
// Kernel 3: output projection. R6 structure (in-block split-K2, 8 waves,
// __launch_bounds__(512,4) — spill-free at VGPR<=128, 16 waves/CU).
// grid = (M/16, 768/256), block = 512.
// ---------------------------------------------------------------------------
template <int PARTS>
__global__ __launch_bounds__(512, 4) void proj_kernel(
    const _Float16* __restrict__ Opart,       // [PARTS][4096][768] fp16
    const float* __restrict__ lpart,          // [PARTS][B*H][S]
    const _Float16* __restrict__ Wob,         // [768][768] fp16
    const float* __restrict__ bo,             // [768] fp32
    float* __restrict__ out)                  // [4096][768] fp32
{
    __shared__ float lds[4 * 64 * 20];        // [wn][n_local 64][m 16 pad 20]

    const int wave = threadIdx.x >> 6;        // 0..7
    const int lane = threadIdx.x & 63;
    const int col  = lane & 15;
    const int quad = lane >> 4;
    const int kg   = wave >> 2;               // 0/1: k-group
    const int wn   = wave & 3;                // n-column
    const int m0   = blockIdx.x * 16;
    const int n0   = blockIdx.y * 256 + wn * 64;

    const int m = m0 + col;
    const int b = m / S_;
    const int s = m - b * S_;
    const float* lpb = lpart + (size_t)(b * H_) * S_ + s;
    const size_t BHS = (size_t)B_ * H_ * S_;
    const size_t BSE = (size_t)B_ * S_ * E_;

    union UA { uint4 u; half2v h[4]; half8 v; };

    f32x4 acc[4] = {{0.f,0.f,0.f,0.f},{0.f,0.f,0.f,0.f},
                    {0.f,0.f,0.f,0.f},{0.f,0.f,0.f,0.f}};

    float lA[PARTS]; UA oA[PARTS]; UA wA[4];
    float lB[PARTS]; UA oB[PARTS]; UA wB[4];

    auto load_a = [&](int k0) {
        const int h = k0 >> 5;
        const size_t aofs = (size_t)m * E_ + k0 + quad * 8;
#pragma unroll
        for (int pp = 0; pp < PARTS; ++pp) {
            lA[pp] = lpb[(size_t)pp * BHS + (size_t)h * S_];
            oA[pp].u = *reinterpret_cast<const uint4*>(
                Opart + (size_t)pp * BSE + aofs);
        }
#pragma unroll
        for (int j = 0; j < 4; ++j)
            wA[j].u = *reinterpret_cast<const uint4*>(
                Wob + (size_t)(n0 + j * 16 + col) * E_ + k0 + quad * 8);
    };
    auto load_b = [&](int k0) {
        const int h = k0 >> 5;
        const size_t aofs = (size_t)m * E_ + k0 + quad * 8;
#pragma unroll
        for (int pp = 0; pp < PARTS; ++pp) {
            lB[pp] = lpb[(size_t)pp * BHS + (size_t)h * S_];
            oB[pp].u = *reinterpret_cast<const uint4*>(
                Opart + (size_t)pp * BSE + aofs);
        }
#pragma unroll
        for (int j = 0; j < 4; ++j)
            wB[j].u = *reinterpret_cast<const uint4*>(
                Wob + (size_t)(n0 + j * 16 + col) * E_ + k0 + quad * 8);
    };
    auto comp_a = [&]() {
        float l = 0.f;
#pragma unroll
        for (int pp = 0; pp < PARTS; ++pp) l += lA[pp];
        const float linv = __builtin_amdgcn_rcpf(l);
        const half2v lv = cvt2h(linv, linv);
        UA ua = oA[0];
#pragma unroll
        for (int pp = 1; pp < PARTS; ++pp)
#pragma unroll
            for (int i = 0; i < 4; ++i) ua.h[i] += oA[pp].h[i];
#pragma unroll
        for (int i = 0; i < 4; ++i) ua.h[i] *= lv;
#pragma unroll
        for (int j = 0; j < 4; ++j)
            acc[j] = __builtin_amdgcn_mfma_f32_16x16x32_f16(ua.v, wA[j].v, acc[j], 0, 0, 0);
    };
    auto comp_b = [&]() {
        float l = 0.f;
#pragma unroll
        for (int pp = 0; pp < PARTS; ++pp) l += lB[pp];
        const float linv = __builtin_amdgcn_rcpf(l);
        const half2v lv = cvt2h(linv, linv);
        UA ua = oB[0];
#pragma unroll
        for (int pp = 1; pp < PARTS; ++pp)
#pragma unroll
            for (int i = 0; i < 4; ++i) ua.h[i] += oB[pp].h[i];
#pragma unroll
        for (int i = 0; i < 4; ++i) ua.h[i] *= lv;
#pragma unroll
        for (int j = 0; j < 4; ++j)
            acc[j] = __builtin_amdgcn_mfma_f32_16x16x32_f16(ua.v, wB[j].v, acc[j], 0, 0, 0);
    };

    const int kbeg = kg * (E_ / 2);           // 0 or 384
    const int kend = kbeg + E_ / 2;
    load_a(kbeg);
    for (int k0 = kbeg; k0 < kend; k0 += 64) {
        load_b(k0 + 32);
        comp_a();
        if (k0 + 64 < kend) load_a(k0 + 64);
        comp_b();
    }

    // split-K combine via LDS (pad 20 breaks the 16-float power-of-2 stride)
    if (kg == 1) {
#pragma unroll
        for (int j = 0; j < 4; ++j) {
            float* lp_ = &lds[((wn * 64 + j * 16 + col) * 20) + quad * 4];
#pragma unroll
            for (int r = 0; r < 4; ++r) lp_[r] = acc[j][r];
        }
    }
    __syncthreads();
    if (kg == 0) {
#pragma unroll
        for (int j = 0; j < 4; ++j) {
            const float* lp_ = &lds[((wn * 64 + j * 16 + col) * 20) + quad * 4];
            const int n = n0 + j * 16 + col;
            const float bias = bo[n];
#pragma unroll
            for (int r = 0; r < 4; ++r) {
                const int mm = m0 + quad * 4 + r;
                out[(size_t)mm * E_ + n] = acc[j][r] + lp_[r] + bias;
            }
        }
    }
}

// ---------------------------------------------------------------------------
extern "C" void kernel_launch(void* const* d_in, const int* in_sizes, int n_in,
                              void* d_out, int out_size, void* d_ws, size_t ws_size,
                              hipStream_t stream)
{
    const float* emb = (const float*)d_in[0];
    const int*   msk = (const int*)d_in[1];
    const float* Wq  = (const float*)d_in[2];
    const float* Wk  = (const float*)d_in[3];
    const float* Wv  = (const float*)d_in[4];
    const float* Wo  = (const float*)d_in[5];
    const float* bo  = (const float*)d_in[6];
    float* out = (float*)d_out;

    const size_t nqkv = (size_t)B_ * H_ * S_ * DH_;   // 3,145,728 (= B*S*E)
    char* p = (char*)d_ws;
    __hip_bfloat16* Q    = (__hip_bfloat16*)p;  p += nqkv * 2;
    __hip_bfloat16* Kp   = (__hip_bfloat16*)p;  p += nqkv * 2;
    _Float16*      Vt    = (_Float16*)p;        p += nqkv * 2;
    unsigned int*  mbits = (unsigned int*)p;    p += (size_t)B_ * S_ * SW_ * 4;
    _Float16*      Wob   = (_Float16*)p;        p += (size_t)E_ * E_ * 2;
    _Float16*      Op    = (_Float16*)p;                      // [parts][B][S][E]
    const size_t base = (size_t)(p - (char*)d_ws);

    // parts = 2 (R4 post-mortem: 4 costs proj more than it gains attn)
    const size_t per_part = (size_t)nqkv * 2 + (size_t)B_ * H_ * S_ * 4;
    int parts = 1;
    if (ws_size >= base + 2 * per_part) parts = 2;
    float* lpart = (float*)(Op + (size_t)parts * nqkv);

    prep_qkv_kernel<<<NB_QKV + NB_MSK4 + NB_WO, 256, 0, stream>>>(
        emb, msk, Wo, Wq, Wk, Wv, Q, Kp, Vt, mbits, Wob);
    attn_kernel<<<1536 * parts, 64, 0, stream>>>(
        Q, Kp, Vt, mbits, Op, lpart, parts);
    if (parts == 2)
        proj_kernel<2><<<dim3((B_ * S_) / 16, E_ / 256), 512, 0, stream>>>(
            Op, lpart, Wob, bo, out);
    else
        proj_kernel<1><<<dim3((B_ * S_) / 16, E_ / 256), 512, 0, stream>>>(
            Op, lpart, Wob, bo, out);
}

// Round 8
// 251.006 us; speedup vs baseline: 1.0388x; 1.0388x over previous
//
#include <hip/hip_runtime.h>
#include <hip/hip_bf16.h>

#define B_  2
#define S_  2048
#define H_  24
#define DH_ 32
#define E_  768
#define SW_ (S_/32)   // mask words per row = 64

#define NB_QKV  ((S_/64)*(B_*H_))      // 1536 blocks (qkv part, dispatched first)
#define NB_MSK4 ((B_*S_*S_)/1024)      // 8192 blocks (4 rows x 64 keys per wave)
#define NB_WO   ((E_*E_)/1024)         // 576 blocks

typedef __attribute__((ext_vector_type(8))) short short8;   // 8 x bf16 bits
typedef __attribute__((ext_vector_type(4))) float f32x4;
typedef _Float16 half8  __attribute__((ext_vector_type(8)));
typedef _Float16 half2v __attribute__((ext_vector_type(2)));
typedef __fp16   fp16x2 __attribute__((ext_vector_type(2)));   // cvt_pkrtz return type

// fp32 pair -> packed fp16 (one v_cvt_pkrtz_f16_f32), as _Float16 vector
static __device__ __forceinline__ half2v cvt2h(float a, float b) {
    fp16x2 t = __builtin_amdgcn_cvt_pkrtz(a, b);
    return __builtin_bit_cast(half2v, t);
}

// 4 floats -> 4 bf16 packed in 8B
static __device__ __forceinline__ short4 pack4(float a, float b, float c, float d) {
    union { __hip_bfloat162 h[2]; short4 s; } u;
    u.h[0] = __float22bfloat162_rn(make_float2(a, b));
    u.h[1] = __float22bfloat162_rn(make_float2(c, d));
    return u.s;
}
static __device__ __forceinline__ short8 pack8f(const float* a, const float* b) {
    union { __hip_bfloat162 h[4]; short8 s; } u;
    u.h[0] = __float22bfloat162_rn(make_float2(a[0], a[1]));
    u.h[1] = __float22bfloat162_rn(make_float2(a[2], a[3]));
    u.h[2] = __float22bfloat162_rn(make_float2(b[0], b[1]));
    u.h[3] = __float22bfloat162_rn(make_float2(b[2], b[3]));
    return u.s;
}
static __device__ __forceinline__ short8 pack8(float4 a, float4 b) {
    union { __hip_bfloat162 h[4]; short8 s; } u;
    u.h[0] = __float22bfloat162_rn(make_float2(a.x, a.y));
    u.h[1] = __float22bfloat162_rn(make_float2(a.z, a.w));
    u.h[2] = __float22bfloat162_rn(make_float2(b.x, b.y));
    u.h[3] = __float22bfloat162_rn(make_float2(b.z, b.w));
    return u.s;
}
// weight fragment straight from fp32 W[h-base][d][e]: F[j] = W[(quad*8+j)*32+eo]
static __device__ __forceinline__ short8 wfrag(const float* __restrict__ Wb,
                                               int quad, int eo) {
    float w[8];
#pragma unroll
    for (int j = 0; j < 8; ++j) w[j] = Wb[(quad * 8 + j) * 32 + eo];
    return pack8f(w, w + 4);
}

// Q pre-scaled by (1/sqrt(32))*log2(e): MFMA scores land in the exp2 domain.
// Mask zeroes x (bitwise AND with sbfe sign-mask) BEFORE exp2; exp2(0) = 1.0
// exactly = exp(-1e-6) at working precision.
#define QSCALE  0.25503487f

// masked-exp2 on one f32 score: m = sext(bit) (0 or -1), x &= m, p = 2^x
static __device__ __forceinline__ float mexp2(float s, unsigned mw, int pos) {
    const int m = __builtin_amdgcn_sbfe((int)mw, pos, 1);     // 0 or 0xFFFFFFFF
    const int xi = __builtin_bit_cast(int, s) & m;
    return __builtin_amdgcn_exp2f(__builtin_bit_cast(float, xi));
}

// ---------------------------------------------------------------------------
// Kernel 0: FUSED prep + qkv (mutually independent parts, one launch).
// Mask part: 4 rows x 64 keys per wave, loads batched before ballots (R4).
// ---------------------------------------------------------------------------
__global__ __launch_bounds__(256) void prep_qkv_kernel(
    const float* __restrict__ x, const int* __restrict__ mask,
    const float* __restrict__ Wo,
    const float* __restrict__ Wq, const float* __restrict__ Wk,
    const float* __restrict__ Wv,
    __hip_bfloat16* __restrict__ Qo,
    __hip_bfloat16* __restrict__ Ko,      // permuted-key layout, bf16
    _Float16* __restrict__ Vto,           // fp16 (PV runs on f16 MFMA)
    unsigned int* __restrict__ mbits, _Float16* __restrict__ Wob)
{
    const int bx = blockIdx.x;
    if (bx < NB_QKV) {
        // ---- QKV: 16 s-rows/wave, 6 MFMAs. K stored PERMUTED within each
        // 32-key tile: key k=8q+4u+i -> slot (u<<4)|(q*4+i) so attn's score
        // MFMAs produce P directly in PV B-operand register layout. ----
        const int bh   = bx >> 5;            // [0,48)
        const int b    = bh / H_;
        const int h    = bh - b * H_;
        const int wave = threadIdx.x >> 6;
        const int lane = threadIdx.x & 63;
        const int col  = lane & 15;
        const int quad = lane >> 4;
        const int sw   = (bx & 31) * 64 + wave * 16;
        const int s    = sw + col;

        const float* xp = x + ((size_t)b * S_ + s) * E_ + h * DH_ + quad * 8;
        const float4 xa = *reinterpret_cast<const float4*>(xp);
        const float4 xb = *reinterpret_cast<const float4*>(xp + 4);
        const short8 xf = pack8(xa, xb);

        const int wb = h * DH_ * DH_;
        const short8 aQ0 = wfrag(Wq + wb, quad, col);
        const short8 aQ1 = wfrag(Wq + wb, quad, col + 16);
        const short8 aK0 = wfrag(Wk + wb, quad, col);
        const short8 aK1 = wfrag(Wk + wb, quad, col + 16);
        const short8 bV0 = wfrag(Wv + wb, quad, col);
        const short8 bV1 = wfrag(Wv + wb, quad, col + 16);

        const f32x4 z = {0.f, 0.f, 0.f, 0.f};
        const f32x4 qt0 = __builtin_amdgcn_mfma_f32_16x16x32_bf16(aQ0, xf, z, 0, 0, 0);
        const f32x4 qt1 = __builtin_amdgcn_mfma_f32_16x16x32_bf16(aQ1, xf, z, 0, 0, 0);
        const f32x4 kt0 = __builtin_amdgcn_mfma_f32_16x16x32_bf16(aK0, xf, z, 0, 0, 0);
        const f32x4 kt1 = __builtin_amdgcn_mfma_f32_16x16x32_bf16(aK1, xf, z, 0, 0, 0);
        const f32x4 vv0 = __builtin_amdgcn_mfma_f32_16x16x32_bf16(xf, bV0, z, 0, 0, 0);
        const f32x4 vv1 = __builtin_amdgcn_mfma_f32_16x16x32_bf16(xf, bV1, z, 0, 0, 0);

        __hip_bfloat16* qrow = Qo + ((size_t)bh * S_ + s) * DH_;
        *reinterpret_cast<short4*>(qrow + quad * 4) =
            pack4(qt0[0] * QSCALE, qt0[1] * QSCALE, qt0[2] * QSCALE, qt0[3] * QSCALE);
        *reinterpret_cast<short4*>(qrow + 16 + quad * 4) =
            pack4(qt1[0] * QSCALE, qt1[1] * QSCALE, qt1[2] * QSCALE, qt1[3] * QSCALE);

        const int t32  = s & 31;
        const int slot = (s & ~31) | (((t32 >> 2) & 1) << 4)
                       | (((t32 >> 3) << 2) | (t32 & 3));
        __hip_bfloat16* krow = Ko + ((size_t)bh * S_ + slot) * DH_;
        *reinterpret_cast<short4*>(krow + quad * 4)      = pack4(kt0[0], kt0[1], kt0[2], kt0[3]);
        *reinterpret_cast<short4*>(krow + 16 + quad * 4) = pack4(kt1[0], kt1[1], kt1[2], kt1[3]);

        const int sb = sw + quad * 4;
        union { half2v h[2]; uint2 u; } v0u, v1u;
        v0u.h[0] = cvt2h(vv0[0], vv0[1]); v0u.h[1] = cvt2h(vv0[2], vv0[3]);
        v1u.h[0] = cvt2h(vv1[0], vv1[1]); v1u.h[1] = cvt2h(vv1[2], vv1[3]);
        *reinterpret_cast<uint2*>(Vto + ((size_t)bh * DH_ + col) * S_ + sb)      = v0u.u;
        *reinterpret_cast<uint2*>(Vto + ((size_t)bh * DH_ + 16 + col) * S_ + sb) = v1u.u;
    } else if (bx < NB_QKV + NB_MSK4) {
        // 4 rows x 64 keys per wave; loads batched before ballots
        const int wid  = (bx - NB_QKV) * 4 + (threadIdx.x >> 6);  // [0, 32768)
        const int lane = threadIdx.x & 63;
        const int rg   = wid >> 5;          // row group of 4, [0, 1024)
        const int kc   = wid & 31;          // 64-key chunk, [0, 32)
        const int row0 = rg * 4;            // global row index (b*S + q)
        const int k    = kc * 64 + lane;
        int mv[4];
#pragma unroll
        for (int j = 0; j < 4; ++j)
            mv[j] = mask[(size_t)(row0 + j) * S_ + k];
#pragma unroll
        for (int j = 0; j < 4; ++j) {
            const unsigned long long bal = __ballot(mv[j] != 0);
            if (lane == 0) {
                uint2 w;
                w.x = (unsigned int)(bal & 0xffffffffull);
                w.y = (unsigned int)(bal >> 32);
                *reinterpret_cast<uint2*>(
                    mbits + (size_t)(row0 + j) * SW_ + kc * 2) = w;
            }
        }
    } else {
        const int i = ((bx - NB_QKV - NB_MSK4) * 256 + threadIdx.x) * 4;
        const float4 w = *reinterpret_cast<const float4*>(Wo + i);
        union { half2v h[2]; uint2 u; } uu;
        uu.h[0] = cvt2h(w.x, w.y);
        uu.h[1] = cvt2h(w.z, w.w);
        *reinterpret_cast<uint2*>(Wob + i) = uu.u;
    }
}

// ---------------------------------------------------------------------------
// Kernel 2: fused attention — R6 body (proven 60.4us: depth-1 K+mask register
// pipeline, V in-phase) + ONLY the zero-register-cost setprio hints around
// MFMA clusters (m191: +4-7% for independent single-wave blocks). R7's
// V-double-buffer + fat lambda caused scratch spill (WRITE_SIZE 260MB) —
// reverted. parts=2, grid = 1536*parts, block = 64.
// ---------------------------------------------------------------------------
__global__ __launch_bounds__(64, 3) void attn_kernel(
    const __hip_bfloat16* __restrict__ Q,     // [B*H][S][DH] (pre-scaled)
    const __hip_bfloat16* __restrict__ K,     // [B*H][S][DH] permuted tiles
    const _Float16* __restrict__ Vt,          // [B*H][DH][S] fp16
    const unsigned int* __restrict__ mbits,   // [B][S][S/32]
    _Float16* __restrict__ Opart,             // [parts][B][S][E] unnormalized
    float* __restrict__ lpart,                // [parts][B*H][S]
    int parts)
{
    const int bid  = blockIdx.x;
    const int xcd  = bid & 7;
    const int t_   = bid >> 3;                 // [0, 6*32*parts)
    const int bh   = xcd * 6 + (t_ % 6);
    const int rest = t_ / 6;                   // [0, 32*parts)
    const int qsub = rest & 31;
    const int part = rest >> 5;

    const int b    = bh / H_;
    const int h    = bh - b * H_;
    const int niter = S_ / (64 * parts);       // 16 (parts=2) — even
    const int kbeg  = part * (S_ / parts);
    const int lane = threadIdx.x & 63;
    const int col  = lane & 15;
    const int quad = lane >> 4;
    const int q0   = qsub * 64;

    const __hip_bfloat16* Qbh = Q  + (size_t)bh * S_ * DH_;
    const __hip_bfloat16* Kbh = K  + (size_t)bh * S_ * DH_;
    const _Float16*       Vbh = Vt + (size_t)bh * DH_ * S_;

    short8 qf[4];
#pragma unroll
    for (int t = 0; t < 4; ++t)
        qf[t] = *reinterpret_cast<const short8*>(
            Qbh + (size_t)(q0 + t * 16 + col) * DH_ + quad * 8);

    const _Float16* Vp0 = Vbh + (size_t)col * S_ + kbeg + quad * 8;
    const _Float16* Vp1 = Vbh + (size_t)(16 + col) * S_ + kbeg + quad * 8;

    // prefetch cursors (advance one tile ahead of compute)
    const __hip_bfloat16* Kf = Kbh + (size_t)(kbeg + col) * DH_ + quad * 8;
    const unsigned int* mbb = mbits + (size_t)b * S_ * SW_ + (kbeg >> 5);
    const unsigned int* mf0 = mbb + (size_t)(q0 +  0 + col) * SW_;
    const unsigned int* mf1 = mbb + (size_t)(q0 + 16 + col) * SW_;
    const unsigned int* mf2 = mbb + (size_t)(q0 + 32 + col) * SW_;
    const unsigned int* mf3 = mbb + (size_t)(q0 + 48 + col) * SW_;

    // sbfe bit positions: low-half keys at quad*8+r, high-half at quad*8+4+r
    const int posL = quad * 8;
    const int posH = quad * 8 + 4;

    union { uint4 u; half8 v; } onesu;
    onesu.u = make_uint4(0x3C003C00u, 0x3C003C00u, 0x3C003C00u, 0x3C003C00u);
    const half8 ones_h = onesu.v;

    f32x4 o0a[4], o1a[4], la[4];
#pragma unroll
    for (int t = 0; t < 4; ++t) {
        o0a[t] = (f32x4){0.f,0.f,0.f,0.f};
        o1a[t] = (f32x4){0.f,0.f,0.f,0.f};
        la[t]  = (f32x4){0.f,0.f,0.f,0.f};
    }

    // double-buffered K-fragments + mask words
    short8 ak0, ak1, ak2, ak3; uint2 am0, am1, am2, am3;
    short8 bk0, bk1, bk2, bk3; uint2 bm0, bm1, bm2, bm3;

    auto load_a = [&]() {
        ak0 = *reinterpret_cast<const short8*>(Kf);
        ak1 = *reinterpret_cast<const short8*>(Kf + 16 * DH_);
        ak2 = *reinterpret_cast<const short8*>(Kf + 32 * DH_);
        ak3 = *reinterpret_cast<const short8*>(Kf + 48 * DH_);
        am0 = *reinterpret_cast<const uint2*>(mf0);
        am1 = *reinterpret_cast<const uint2*>(mf1);
        am2 = *reinterpret_cast<const uint2*>(mf2);
        am3 = *reinterpret_cast<const uint2*>(mf3);
        Kf += 64 * DH_; mf0 += 2; mf1 += 2; mf2 += 2; mf3 += 2;
    };
    auto load_b = [&]() {
        bk0 = *reinterpret_cast<const short8*>(Kf);
        bk1 = *reinterpret_cast<const short8*>(Kf + 16 * DH_);
        bk2 = *reinterpret_cast<const short8*>(Kf + 32 * DH_);
        bk3 = *reinterpret_cast<const short8*>(Kf + 48 * DH_);
        bm0 = *reinterpret_cast<const uint2*>(mf0);
        bm1 = *reinterpret_cast<const uint2*>(mf1);
        bm2 = *reinterpret_cast<const uint2*>(mf2);
        bm3 = *reinterpret_cast<const uint2*>(mf3);
        Kf += 64 * DH_; mf0 += 2; mf1 += 2; mf2 += 2; mf3 += 2;
    };

    auto compute = [&](const short8& kA0, const short8& kA1,
                       const short8& kB0, const short8& kB1,
                       uint2 w0, uint2 w1, uint2 w2, uint2 w3) {
        const half8 vA0 = *reinterpret_cast<const half8*>(Vp0);
        const half8 vA1 = *reinterpret_cast<const half8*>(Vp1);
        const half8 vB0 = *reinterpret_cast<const half8*>(Vp0 + 32);
        const half8 vB1 = *reinterpret_cast<const half8*>(Vp1 + 32);
        const uint2 mw[4] = {w0, w1, w2, w3};
        const f32x4 z = {0.f, 0.f, 0.f, 0.f};

        // ---- subtile A (keys +0..31) ----
        f32x4 s0[4], s1[4];
        __builtin_amdgcn_s_setprio(1);
#pragma unroll
        for (int t = 0; t < 4; ++t) {
            s0[t] = __builtin_amdgcn_mfma_f32_16x16x32_bf16(kA0, qf[t], z, 0, 0, 0);
            s1[t] = __builtin_amdgcn_mfma_f32_16x16x32_bf16(kA1, qf[t], z, 0, 0, 0);
        }
        __builtin_amdgcn_s_setprio(0);
#pragma unroll
        for (int t = 0; t < 4; ++t) {
            float p0[4], p1[4];
#pragma unroll
            for (int r = 0; r < 4; ++r) {
                p0[r] = mexp2(s0[t][r], mw[t].x, posL + r);
                p1[r] = mexp2(s1[t][r], mw[t].x, posH + r);
            }
            union { half2v h[4]; half8 v; } pu;
            pu.h[0] = cvt2h(p0[0], p0[1]);
            pu.h[1] = cvt2h(p0[2], p0[3]);
            pu.h[2] = cvt2h(p1[0], p1[1]);
            pu.h[3] = cvt2h(p1[2], p1[3]);
            const half8 pf = pu.v;
            __builtin_amdgcn_s_setprio(1);
            o0a[t] = __builtin_amdgcn_mfma_f32_16x16x32_f16(vA0, pf, o0a[t], 0, 0, 0);
            o1a[t] = __builtin_amdgcn_mfma_f32_16x16x32_f16(vA1, pf, o1a[t], 0, 0, 0);
            la[t]  = __builtin_amdgcn_mfma_f32_16x16x32_f16(ones_h, pf, la[t], 0, 0, 0);
            __builtin_amdgcn_s_setprio(0);
        }

        // ---- subtile B (keys +32..63) ----
        __builtin_amdgcn_s_setprio(1);
#pragma unroll
        for (int t = 0; t < 4; ++t) {
            s0[t] = __builtin_amdgcn_mfma_f32_16x16x32_bf16(kB0, qf[t], z, 0, 0, 0);
            s1[t] = __builtin_amdgcn_mfma_f32_16x16x32_bf16(kB1, qf[t], z, 0, 0, 0);
        }
        __builtin_amdgcn_s_setprio(0);
#pragma unroll
        for (int t = 0; t < 4; ++t) {
            float p0[4], p1[4];
#pragma unroll
            for (int r = 0; r < 4; ++r) {
                p0[r] = mexp2(s0[t][r], mw[t].y, posL + r);
                p1[r] = mexp2(s1[t][r], mw[t].y, posH + r);
            }
            union { half2v h[4]; half8 v; } pu;
            pu.h[0] = cvt2h(p0[0], p0[1]);
            pu.h[1] = cvt2h(p0[2], p0[3]);
            pu.h[2] = cvt2h(p1[0], p1[1]);
            pu.h[3] = cvt2h(p1[2], p1[3]);
            const half8 pf = pu.v;
            __builtin_amdgcn_s_setprio(1);
            o0a[t] = __builtin_amdgcn_mfma_f32_16x16x32_f16(vB0, pf, o0a[t], 0, 0, 0);
            o1a[t] = __builtin_amdgcn_mfma_f32_16x16x32_f16(vB1, pf, o1a[t], 0, 0, 0);
            la[t]  = __builtin_amdgcn_mfma_f32_16x16x32_f16(ones_h, pf, la[t], 0, 0, 0);
            __builtin_amdgcn_s_setprio(0);
        }

        Vp0 += 64;
        Vp1 += 64;
    };

    // software pipeline: prefetch depth 1, 2x-unrolled rotation
    load_a();
    for (int it = 0; it < niter; it += 2) {
        load_b();                                    // tile it+1
        compute(ak0, ak1, ak2, ak3, am0, am1, am2, am3);
        load_a();                                    // tile it+2 (overrun on last pair: unused)
        compute(bk0, bk1, bk2, bk3, bm0, bm1, bm2, bm3);
    }

    _Float16* Ob = Opart + (size_t)part * B_ * S_ * E_;
    float* lp = lpart + (size_t)part * B_ * H_ * S_ + (size_t)bh * S_;
#pragma unroll
    for (int t = 0; t < 4; ++t) {
        union { half2v h[2]; uint2 u; } u0, u1;
        u0.h[0] = cvt2h(o0a[t][0], o0a[t][1]);
        u0.h[1] = cvt2h(o0a[t][2], o0a[t][3]);
        u1.h[0] = cvt2h(o1a[t][0], o1a[t][1]);
        u1.h[1] = cvt2h(o1a[t][2], o1a[t][3]);
        _Float16* orow = Ob + ((size_t)b * S_ + q0 + t * 16 + col) * E_ + h * DH_;
        *reinterpret_cast<uint2*>(orow + quad * 4)      = u0.u;
        *reinterpret_cast<uint2*>(orow + 16 + quad * 4) = u1.u;
        if (quad == 0) lp[q0 + t * 16 + col] = la[t][0];
    }
}

// ---------------------------------------------------------------------------
// Kernel 3: output projection. R6 structure (in-block split-K2, 8 waves,
// __launch_bounds__(512,4) — spill-free at VGPR<=128, 16 waves/CU).
// grid = (M/16, 768/256), block = 512.
// ---------------------------------------------------------------------------
template <int PARTS>
__global__ __launch_bounds__(512, 4) void proj_kernel(
    const _Float16* __restrict__ Opart,       // [PARTS][4096][768] fp16
    const float* __restrict__ lpart,          // [PARTS][B*H][S]
    const _Float16* __restrict__ Wob,         // [768][768] fp16
    const float* __restrict__ bo,             // [768] fp32
    float* __restrict__ out)                  // [4096][768] fp32
{
    __shared__ float lds[4 * 64 * 20];        // [wn][n_local 64][m 16 pad 20]

    const int wave = threadIdx.x >> 6;        // 0..7
    const int lane = threadIdx.x & 63;
    const int col  = lane & 15;
    const int quad = lane >> 4;
    const int kg   = wave >> 2;               // 0/1: k-group
    const int wn   = wave & 3;                // n-column
    const int m0   = blockIdx.x * 16;
    const int n0   = blockIdx.y * 256 + wn * 64;

    const int m = m0 + col;
    const int b = m / S_;
    const int s = m - b * S_;
    const float* lpb = lpart + (size_t)(b * H_) * S_ + s;
    const size_t BHS = (size_t)B_ * H_ * S_;
    const size_t BSE = (size_t)B_ * S_ * E_;

    union UA { uint4 u; half2v h[4]; half8 v; };

    f32x4 acc[4] = {{0.f,0.f,0.f,0.f},{0.f,0.f,0.f,0.f},
                    {0.f,0.f,0.f,0.f},{0.f,0.f,0.f,0.f}};

    float lA[PARTS]; UA oA[PARTS]; UA wA[4];
    float lB[PARTS]; UA oB[PARTS]; UA wB[4];

    auto load_a = [&](int k0) {
        const int h = k0 >> 5;
        const size_t aofs = (size_t)m * E_ + k0 + quad * 8;
#pragma unroll
        for (int pp = 0; pp < PARTS; ++pp) {
            lA[pp] = lpb[(size_t)pp * BHS + (size_t)h * S_];
            oA[pp].u = *reinterpret_cast<const uint4*>(
                Opart + (size_t)pp * BSE + aofs);
        }
#pragma unroll
        for (int j = 0; j < 4; ++j)
            wA[j].u = *reinterpret_cast<const uint4*>(
                Wob + (size_t)(n0 + j * 16 + col) * E_ + k0 + quad * 8);
    };
    auto load_b = [&](int k0) {
        const int h = k0 >> 5;
        const size_t aofs = (size_t)m * E_ + k0 + quad * 8;
#pragma unroll
        for (int pp = 0; pp < PARTS; ++pp) {
            lB[pp] = lpb[(size_t)pp * BHS + (size_t)h * S_];
            oB[pp].u = *reinterpret_cast<const uint4*>(
                Opart + (size_t)pp * BSE + aofs);
        }
#pragma unroll
        for (int j = 0; j < 4; ++j)
            wB[j].u = *reinterpret_cast<const uint4*>(
                Wob + (size_t)(n0 + j * 16 + col) * E_ + k0 + quad * 8);
    };
    auto comp_a = [&]() {
        float l = 0.f;
#pragma unroll
        for (int pp = 0; pp < PARTS; ++pp) l += lA[pp];
        const float linv = __builtin_amdgcn_rcpf(l);
        const half2v lv = cvt2h(linv, linv);
        UA ua = oA[0];
#pragma unroll
        for (int pp = 1; pp < PARTS; ++pp)
#pragma unroll
            for (int i = 0; i < 4; ++i) ua.h[i] += oA[pp].h[i];
#pragma unroll
        for (int i = 0; i < 4; ++i) ua.h[i] *= lv;
#pragma unroll
        for (int j = 0; j < 4; ++j)
            acc[j] = __builtin_amdgcn_mfma_f32_16x16x32_f16(ua.v, wA[j].v, acc[j], 0, 0, 0);
    };
    auto comp_b = [&]() {
        float l = 0.f;
#pragma unroll
        for (int pp = 0; pp < PARTS; ++pp) l += lB[pp];
        const float linv = __builtin_amdgcn_rcpf(l);
        const half2v lv = cvt2h(linv, linv);
        UA ua = oB[0];
#pragma unroll
        for (int pp = 1; pp < PARTS; ++pp)
#pragma unroll
            for (int i = 0; i < 4; ++i) ua.h[i] += oB[pp].h[i];
#pragma unroll
        for (int i = 0; i < 4; ++i) ua.h[i] *= lv;
#pragma unroll
        for (int j = 0; j < 4; ++j)
            acc[j] = __builtin_amdgcn_mfma_f32_16x16x32_f16(ua.v, wB[j].v, acc[j], 0, 0, 0);
    };

    const int kbeg = kg * (E_ / 2);           // 0 or 384
    const int kend = kbeg + E_ / 2;
    load_a(kbeg);
    for (int k0 = kbeg; k0 < kend; k0 += 64) {
        load_b(k0 + 32);
        comp_a();
        if (k0 + 64 < kend) load_a(k0 + 64);
        comp_b();
    }

    // split-K combine via LDS (pad 20 breaks the 16-float power-of-2 stride)
    if (kg == 1) {
#pragma unroll
        for (int j = 0; j < 4; ++j) {
            float* lp_ = &lds[((wn * 64 + j * 16 + col) * 20) + quad * 4];
#pragma unroll
            for (int r = 0; r < 4; ++r) lp_[r] = acc[j][r];
        }
    }
    __syncthreads();
    if (kg == 0) {
#pragma unroll
        for (int j = 0; j < 4; ++j) {
            const float* lp_ = &lds[((wn * 64 + j * 16 + col) * 20) + quad * 4];
            const int n = n0 + j * 16 + col;
            const float bias = bo[n];
#pragma unroll
            for (int r = 0; r < 4; ++r) {
                const int mm = m0 + quad * 4 + r;
                out[(size_t)mm * E_ + n] = acc[j][r] + lp_[r] + bias;
            }
        }
    }
}

// ---------------------------------------------------------------------------
extern "C" void kernel_launch(void* const* d_in, const int* in_sizes, int n_in,
                              void* d_out, int out_size, void* d_ws, size_t ws_size,
                              hipStream_t stream)
{
    const float* emb = (const float*)d_in[0];
    const int*   msk = (const int*)d_in[1];
    const float* Wq  = (const float*)d_in[2];
    const float* Wk  = (const float*)d_in[3];
    const float* Wv  = (const float*)d_in[4];
    const float* Wo  = (const float*)d_in[5];
    const float* bo  = (const float*)d_in[6];
    float* out = (float*)d_out;

    const size_t nqkv = (size_t)B_ * H_ * S_ * DH_;   // 3,145,728 (= B*S*E)
    char* p = (char*)d_ws;
    __hip_bfloat16* Q    = (__hip_bfloat16*)p;  p += nqkv * 2;
    __hip_bfloat16* Kp   = (__hip_bfloat16*)p;  p += nqkv * 2;
    _Float16*      Vt    = (_Float16*)p;        p += nqkv * 2;
    unsigned int*  mbits = (unsigned int*)p;    p += (size_t)B_ * S_ * SW_ * 4;
    _Float16*      Wob   = (_Float16*)p;        p += (size_t)E_ * E_ * 2;
    _Float16*      Op    = (_Float16*)p;                      // [parts][B][S][E]
    const size_t base = (size_t)(p - (char*)d_ws);

    // parts = 2 (R4 post-mortem: 4 costs proj more than it gains attn)
    const size_t per_part = (size_t)nqkv * 2 + (size_t)B_ * H_ * S_ * 4;
    int parts = 1;
    if (ws_size >= base + 2 * per_part) parts = 2;
    float* lpart = (float*)(Op + (size_t)parts * nqkv);

    prep_qkv_kernel<<<NB_QKV + NB_MSK4 + NB_WO, 256, 0, stream>>>(
        emb, msk, Wo, Wq, Wk, Wv, Q, Kp, Vt, mbits, Wob);
    attn_kernel<<<1536 * parts, 64, 0, stream>>>(
        Q, Kp, Vt, mbits, Op, lpart, parts);
    if (parts == 2)
        proj_kernel<2><<<dim3((B_ * S_) / 16, E_ / 256), 512, 0, stream>>>(
            Op, lpart, Wob, bo, out);
    else
        proj_kernel<1><<<dim3((B_ * S_) / 16, E_ / 256), 512, 0, stream>>>(
            Op, lpart, Wob, bo, out);
}

// Round 9
// 208.407 us; speedup vs baseline: 1.2511x; 1.2044x over previous
//
#include <hip/hip_runtime.h>
#include <hip/hip_bf16.h>

#define B_  2
#define S_  2048
#define H_  24
#define DH_ 32
#define E_  768
#define SW_ (S_/32)   // mask words per row = 64

#define NB_QKV  ((S_/64)*(B_*H_))      // 1536 blocks (qkv part, dispatched first)
#define NB_MSK4 ((B_*S_*S_)/1024)      // 8192 blocks (4 rows x 64 keys per wave)
#define NB_WO   ((E_*E_)/1024)         // 576 blocks

typedef __attribute__((ext_vector_type(8))) short short8;   // 8 x bf16 bits
typedef __attribute__((ext_vector_type(4))) float f32x4;
typedef _Float16 half8  __attribute__((ext_vector_type(8)));
typedef _Float16 half2v __attribute__((ext_vector_type(2)));
typedef __fp16   fp16x2 __attribute__((ext_vector_type(2)));   // cvt_pkrtz return type

// fp32 pair -> packed fp16 (one v_cvt_pkrtz_f16_f32), as _Float16 vector
static __device__ __forceinline__ half2v cvt2h(float a, float b) {
    fp16x2 t = __builtin_amdgcn_cvt_pkrtz(a, b);
    return __builtin_bit_cast(half2v, t);
}

// 4 floats -> 4 bf16 packed in 8B
static __device__ __forceinline__ short4 pack4(float a, float b, float c, float d) {
    union { __hip_bfloat162 h[2]; short4 s; } u;
    u.h[0] = __float22bfloat162_rn(make_float2(a, b));
    u.h[1] = __float22bfloat162_rn(make_float2(c, d));
    return u.s;
}
static __device__ __forceinline__ short8 pack8f(const float* a, const float* b) {
    union { __hip_bfloat162 h[4]; short8 s; } u;
    u.h[0] = __float22bfloat162_rn(make_float2(a[0], a[1]));
    u.h[1] = __float22bfloat162_rn(make_float2(a[2], a[3]));
    u.h[2] = __float22bfloat162_rn(make_float2(b[0], b[1]));
    u.h[3] = __float22bfloat162_rn(make_float2(b[2], b[3]));
    return u.s;
}
static __device__ __forceinline__ short8 pack8(float4 a, float4 b) {
    union { __hip_bfloat162 h[4]; short8 s; } u;
    u.h[0] = __float22bfloat162_rn(make_float2(a.x, a.y));
    u.h[1] = __float22bfloat162_rn(make_float2(a.z, a.w));
    u.h[2] = __float22bfloat162_rn(make_float2(b.x, b.y));
    u.h[3] = __float22bfloat162_rn(make_float2(b.z, b.w));
    return u.s;
}
// weight fragment straight from fp32 W[h-base][d][e]: F[j] = W[(quad*8+j)*32+eo]
static __device__ __forceinline__ short8 wfrag(const float* __restrict__ Wb,
                                               int quad, int eo) {
    float w[8];
#pragma unroll
    for (int j = 0; j < 8; ++j) w[j] = Wb[(quad * 8 + j) * 32 + eo];
    return pack8f(w, w + 4);
}

// Q pre-scaled by (1/sqrt(32))*log2(e): MFMA scores land in the exp2 domain.
// Mask zeroes x (bitwise AND with sbfe sign-mask) BEFORE exp2; exp2(0) = 1.0
// exactly = exp(-1e-6) at working precision.
#define QSCALE  0.25503487f

// masked-exp2 on one f32 score: m = sext(bit) (0 or -1), x &= m, p = 2^x
static __device__ __forceinline__ float mexp2(float s, unsigned mw, int pos) {
    const int m = __builtin_amdgcn_sbfe((int)mw, pos, 1);     // 0 or 0xFFFFFFFF
    const int xi = __builtin_bit_cast(int, s) & m;
    return __builtin_amdgcn_exp2f(__builtin_bit_cast(float, xi));
}

// ---------------------------------------------------------------------------
// Kernel 0: FUSED prep + qkv (mutually independent parts, one launch).
// Mask part: 4 rows x 64 keys per wave, loads batched before ballots (R4).
// ---------------------------------------------------------------------------
__global__ __launch_bounds__(256) void prep_qkv_kernel(
    const float* __restrict__ x, const int* __restrict__ mask,
    const float* __restrict__ Wo,
    const float* __restrict__ Wq, const float* __restrict__ Wk,
    const float* __restrict__ Wv,
    __hip_bfloat16* __restrict__ Qo,
    __hip_bfloat16* __restrict__ Ko,      // permuted-key layout, bf16
    _Float16* __restrict__ Vto,           // fp16 (PV runs on f16 MFMA)
    unsigned int* __restrict__ mbits, _Float16* __restrict__ Wob)
{
    const int bx = blockIdx.x;
    if (bx < NB_QKV) {
        // ---- QKV: 16 s-rows/wave, 6 MFMAs. K stored PERMUTED within each
        // 32-key tile: key k=8q+4u+i -> slot (u<<4)|(q*4+i) so attn's score
        // MFMAs produce P directly in PV B-operand register layout. ----
        const int bh   = bx >> 5;            // [0,48)
        const int b    = bh / H_;
        const int h    = bh - b * H_;
        const int wave = threadIdx.x >> 6;
        const int lane = threadIdx.x & 63;
        const int col  = lane & 15;
        const int quad = lane >> 4;
        const int sw   = (bx & 31) * 64 + wave * 16;
        const int s    = sw + col;

        const float* xp = x + ((size_t)b * S_ + s) * E_ + h * DH_ + quad * 8;
        const float4 xa = *reinterpret_cast<const float4*>(xp);
        const float4 xb = *reinterpret_cast<const float4*>(xp + 4);
        const short8 xf = pack8(xa, xb);

        const int wb = h * DH_ * DH_;
        const short8 aQ0 = wfrag(Wq + wb, quad, col);
        const short8 aQ1 = wfrag(Wq + wb, quad, col + 16);
        const short8 aK0 = wfrag(Wk + wb, quad, col);
        const short8 aK1 = wfrag(Wk + wb, quad, col + 16);
        const short8 bV0 = wfrag(Wv + wb, quad, col);
        const short8 bV1 = wfrag(Wv + wb, quad, col + 16);

        const f32x4 z = {0.f, 0.f, 0.f, 0.f};
        const f32x4 qt0 = __builtin_amdgcn_mfma_f32_16x16x32_bf16(aQ0, xf, z, 0, 0, 0);
        const f32x4 qt1 = __builtin_amdgcn_mfma_f32_16x16x32_bf16(aQ1, xf, z, 0, 0, 0);
        const f32x4 kt0 = __builtin_amdgcn_mfma_f32_16x16x32_bf16(aK0, xf, z, 0, 0, 0);
        const f32x4 kt1 = __builtin_amdgcn_mfma_f32_16x16x32_bf16(aK1, xf, z, 0, 0, 0);
        const f32x4 vv0 = __builtin_amdgcn_mfma_f32_16x16x32_bf16(xf, bV0, z, 0, 0, 0);
        const f32x4 vv1 = __builtin_amdgcn_mfma_f32_16x16x32_bf16(xf, bV1, z, 0, 0, 0);

        __hip_bfloat16* qrow = Qo + ((size_t)bh * S_ + s) * DH_;
        *reinterpret_cast<short4*>(qrow + quad * 4) =
            pack4(qt0[0] * QSCALE, qt0[1] * QSCALE, qt0[2] * QSCALE, qt0[3] * QSCALE);
        *reinterpret_cast<short4*>(qrow + 16 + quad * 4) =
            pack4(qt1[0] * QSCALE, qt1[1] * QSCALE, qt1[2] * QSCALE, qt1[3] * QSCALE);

        const int t32  = s & 31;
        const int slot = (s & ~31) | (((t32 >> 2) & 1) << 4)
                       | (((t32 >> 3) << 2) | (t32 & 3));
        __hip_bfloat16* krow = Ko + ((size_t)bh * S_ + slot) * DH_;
        *reinterpret_cast<short4*>(krow + quad * 4)      = pack4(kt0[0], kt0[1], kt0[2], kt0[3]);
        *reinterpret_cast<short4*>(krow + 16 + quad * 4) = pack4(kt1[0], kt1[1], kt1[2], kt1[3]);

        const int sb = sw + quad * 4;
        union { half2v h[2]; uint2 u; } v0u, v1u;
        v0u.h[0] = cvt2h(vv0[0], vv0[1]); v0u.h[1] = cvt2h(vv0[2], vv0[3]);
        v1u.h[0] = cvt2h(vv1[0], vv1[1]); v1u.h[1] = cvt2h(vv1[2], vv1[3]);
        *reinterpret_cast<uint2*>(Vto + ((size_t)bh * DH_ + col) * S_ + sb)      = v0u.u;
        *reinterpret_cast<uint2*>(Vto + ((size_t)bh * DH_ + 16 + col) * S_ + sb) = v1u.u;
    } else if (bx < NB_QKV + NB_MSK4) {
        // 4 rows x 64 keys per wave; loads batched before ballots
        const int wid  = (bx - NB_QKV) * 4 + (threadIdx.x >> 6);  // [0, 32768)
        const int lane = threadIdx.x & 63;
        const int rg   = wid >> 5;          // row group of 4, [0, 1024)
        const int kc   = wid & 31;          // 64-key chunk, [0, 32)
        const int row0 = rg * 4;            // global row index (b*S + q)
        const int k    = kc * 64 + lane;
        int mv[4];
#pragma unroll
        for (int j = 0; j < 4; ++j)
            mv[j] = mask[(size_t)(row0 + j) * S_ + k];
#pragma unroll
        for (int j = 0; j < 4; ++j) {
            const unsigned long long bal = __ballot(mv[j] != 0);
            if (lane == 0) {
                uint2 w;
                w.x = (unsigned int)(bal & 0xffffffffull);
                w.y = (unsigned int)(bal >> 32);
                *reinterpret_cast<uint2*>(
                    mbits + (size_t)(row0 + j) * SW_ + kc * 2) = w;
            }
        }
    } else {
        const int i = ((bx - NB_QKV - NB_MSK4) * 256 + threadIdx.x) * 4;
        const float4 w = *reinterpret_cast<const float4*>(Wo + i);
        union { half2v h[2]; uint2 u; } uu;
        uu.h[0] = cvt2h(w.x, w.y);
        uu.h[1] = cvt2h(w.z, w.w);
        *reinterpret_cast<uint2*>(Wob + i) = uu.u;
    }
}

// ---------------------------------------------------------------------------
// Kernel 2: fused attention — EXACT R6 body (proven 60.4us, clean counters).
// FROZEN: R7 (V-dbuf + fat lambda) and R8 (setprio fences) both tipped this
// kernel over a regalloc cliff into scratch spill (WRITE_SIZE 260/209 MB).
// Depth-1 K+mask register pipeline, V in-phase, masked-exp2, parts=2.
// grid = 1536*parts, block = 64.
// ---------------------------------------------------------------------------
__global__ __launch_bounds__(64, 3) void attn_kernel(
    const __hip_bfloat16* __restrict__ Q,     // [B*H][S][DH] (pre-scaled)
    const __hip_bfloat16* __restrict__ K,     // [B*H][S][DH] permuted tiles
    const _Float16* __restrict__ Vt,          // [B*H][DH][S] fp16
    const unsigned int* __restrict__ mbits,   // [B][S][S/32]
    _Float16* __restrict__ Opart,             // [parts][B][S][E] unnormalized
    float* __restrict__ lpart,                // [parts][B*H][S]
    int parts)
{
    const int bid  = blockIdx.x;
    const int xcd  = bid & 7;
    const int t_   = bid >> 3;                 // [0, 6*32*parts)
    const int bh   = xcd * 6 + (t_ % 6);
    const int rest = t_ / 6;                   // [0, 32*parts)
    const int qsub = rest & 31;
    const int part = rest >> 5;

    const int b    = bh / H_;
    const int h    = bh - b * H_;
    const int niter = S_ / (64 * parts);       // 16 (parts=2) — even
    const int kbeg  = part * (S_ / parts);
    const int lane = threadIdx.x & 63;
    const int col  = lane & 15;
    const int quad = lane >> 4;
    const int q0   = qsub * 64;

    const __hip_bfloat16* Qbh = Q  + (size_t)bh * S_ * DH_;
    const __hip_bfloat16* Kbh = K  + (size_t)bh * S_ * DH_;
    const _Float16*       Vbh = Vt + (size_t)bh * DH_ * S_;

    short8 qf[4];
#pragma unroll
    for (int t = 0; t < 4; ++t)
        qf[t] = *reinterpret_cast<const short8*>(
            Qbh + (size_t)(q0 + t * 16 + col) * DH_ + quad * 8);

    const _Float16* Vp0 = Vbh + (size_t)col * S_ + kbeg + quad * 8;
    const _Float16* Vp1 = Vbh + (size_t)(16 + col) * S_ + kbeg + quad * 8;

    // prefetch cursors (advance one tile ahead of compute)
    const __hip_bfloat16* Kf = Kbh + (size_t)(kbeg + col) * DH_ + quad * 8;
    const unsigned int* mbb = mbits + (size_t)b * S_ * SW_ + (kbeg >> 5);
    const unsigned int* mf0 = mbb + (size_t)(q0 +  0 + col) * SW_;
    const unsigned int* mf1 = mbb + (size_t)(q0 + 16 + col) * SW_;
    const unsigned int* mf2 = mbb + (size_t)(q0 + 32 + col) * SW_;
    const unsigned int* mf3 = mbb + (size_t)(q0 + 48 + col) * SW_;

    // sbfe bit positions: low-half keys at quad*8+r, high-half at quad*8+4+r
    const int posL = quad * 8;
    const int posH = quad * 8 + 4;

    union { uint4 u; half8 v; } onesu;
    onesu.u = make_uint4(0x3C003C00u, 0x3C003C00u, 0x3C003C00u, 0x3C003C00u);
    const half8 ones_h = onesu.v;

    f32x4 o0a[4], o1a[4], la[4];
#pragma unroll
    for (int t = 0; t < 4; ++t) {
        o0a[t] = (f32x4){0.f,0.f,0.f,0.f};
        o1a[t] = (f32x4){0.f,0.f,0.f,0.f};
        la[t]  = (f32x4){0.f,0.f,0.f,0.f};
    }

    // double-buffered K-fragments + mask words
    short8 ak0, ak1, ak2, ak3; uint2 am0, am1, am2, am3;
    short8 bk0, bk1, bk2, bk3; uint2 bm0, bm1, bm2, bm3;

    auto load_a = [&]() {
        ak0 = *reinterpret_cast<const short8*>(Kf);
        ak1 = *reinterpret_cast<const short8*>(Kf + 16 * DH_);
        ak2 = *reinterpret_cast<const short8*>(Kf + 32 * DH_);
        ak3 = *reinterpret_cast<const short8*>(Kf + 48 * DH_);
        am0 = *reinterpret_cast<const uint2*>(mf0);
        am1 = *reinterpret_cast<const uint2*>(mf1);
        am2 = *reinterpret_cast<const uint2*>(mf2);
        am3 = *reinterpret_cast<const uint2*>(mf3);
        Kf += 64 * DH_; mf0 += 2; mf1 += 2; mf2 += 2; mf3 += 2;
    };
    auto load_b = [&]() {
        bk0 = *reinterpret_cast<const short8*>(Kf);
        bk1 = *reinterpret_cast<const short8*>(Kf + 16 * DH_);
        bk2 = *reinterpret_cast<const short8*>(Kf + 32 * DH_);
        bk3 = *reinterpret_cast<const short8*>(Kf + 48 * DH_);
        bm0 = *reinterpret_cast<const uint2*>(mf0);
        bm1 = *reinterpret_cast<const uint2*>(mf1);
        bm2 = *reinterpret_cast<const uint2*>(mf2);
        bm3 = *reinterpret_cast<const uint2*>(mf3);
        Kf += 64 * DH_; mf0 += 2; mf1 += 2; mf2 += 2; mf3 += 2;
    };

    auto compute = [&](const short8& kA0, const short8& kA1,
                       const short8& kB0, const short8& kB1,
                       uint2 w0, uint2 w1, uint2 w2, uint2 w3) {
        const half8 vA0 = *reinterpret_cast<const half8*>(Vp0);
        const half8 vA1 = *reinterpret_cast<const half8*>(Vp1);
        const half8 vB0 = *reinterpret_cast<const half8*>(Vp0 + 32);
        const half8 vB1 = *reinterpret_cast<const half8*>(Vp1 + 32);
        const uint2 mw[4] = {w0, w1, w2, w3};
        const f32x4 z = {0.f, 0.f, 0.f, 0.f};

        // ---- subtile A (keys +0..31) ----
        f32x4 s0[4], s1[4];
#pragma unroll
        for (int t = 0; t < 4; ++t) {
            s0[t] = __builtin_amdgcn_mfma_f32_16x16x32_bf16(kA0, qf[t], z, 0, 0, 0);
            s1[t] = __builtin_amdgcn_mfma_f32_16x16x32_bf16(kA1, qf[t], z, 0, 0, 0);
        }
#pragma unroll
        for (int t = 0; t < 4; ++t) {
            float p0[4], p1[4];
#pragma unroll
            for (int r = 0; r < 4; ++r) {
                p0[r] = mexp2(s0[t][r], mw[t].x, posL + r);
                p1[r] = mexp2(s1[t][r], mw[t].x, posH + r);
            }
            union { half2v h[4]; half8 v; } pu;
            pu.h[0] = cvt2h(p0[0], p0[1]);
            pu.h[1] = cvt2h(p0[2], p0[3]);
            pu.h[2] = cvt2h(p1[0], p1[1]);
            pu.h[3] = cvt2h(p1[2], p1[3]);
            const half8 pf = pu.v;
            o0a[t] = __builtin_amdgcn_mfma_f32_16x16x32_f16(vA0, pf, o0a[t], 0, 0, 0);
            o1a[t] = __builtin_amdgcn_mfma_f32_16x16x32_f16(vA1, pf, o1a[t], 0, 0, 0);
            la[t]  = __builtin_amdgcn_mfma_f32_16x16x32_f16(ones_h, pf, la[t], 0, 0, 0);
        }

        // ---- subtile B (keys +32..63) ----
#pragma unroll
        for (int t = 0; t < 4; ++t) {
            s0[t] = __builtin_amdgcn_mfma_f32_16x16x32_bf16(kB0, qf[t], z, 0, 0, 0);
            s1[t] = __builtin_amdgcn_mfma_f32_16x16x32_bf16(kB1, qf[t], z, 0, 0, 0);
        }
#pragma unroll
        for (int t = 0; t < 4; ++t) {
            float p0[4], p1[4];
#pragma unroll
            for (int r = 0; r < 4; ++r) {
                p0[r] = mexp2(s0[t][r], mw[t].y, posL + r);
                p1[r] = mexp2(s1[t][r], mw[t].y, posH + r);
            }
            union { half2v h[4]; half8 v; } pu;
            pu.h[0] = cvt2h(p0[0], p0[1]);
            pu.h[1] = cvt2h(p0[2], p0[3]);
            pu.h[2] = cvt2h(p1[0], p1[1]);
            pu.h[3] = cvt2h(p1[2], p1[3]);
            const half8 pf = pu.v;
            o0a[t] = __builtin_amdgcn_mfma_f32_16x16x32_f16(vB0, pf, o0a[t], 0, 0, 0);
            o1a[t] = __builtin_amdgcn_mfma_f32_16x16x32_f16(vB1, pf, o1a[t], 0, 0, 0);
            la[t]  = __builtin_amdgcn_mfma_f32_16x16x32_f16(ones_h, pf, la[t], 0, 0, 0);
        }

        Vp0 += 64;
        Vp1 += 64;
    };

    // software pipeline: prefetch depth 1, 2x-unrolled rotation
    load_a();
    for (int it = 0; it < niter; it += 2) {
        load_b();                                    // tile it+1
        compute(ak0, ak1, ak2, ak3, am0, am1, am2, am3);
        load_a();                                    // tile it+2 (overrun on last pair: unused)
        compute(bk0, bk1, bk2, bk3, bm0, bm1, bm2, bm3);
    }

    _Float16* Ob = Opart + (size_t)part * B_ * S_ * E_;
    float* lp = lpart + (size_t)part * B_ * H_ * S_ + (size_t)bh * S_;
#pragma unroll
    for (int t = 0; t < 4; ++t) {
        union { half2v h[2]; uint2 u; } u0, u1;
        u0.h[0] = cvt2h(o0a[t][0], o0a[t][1]);
        u0.h[1] = cvt2h(o0a[t][2], o0a[t][3]);
        u1.h[0] = cvt2h(o1a[t][0], o1a[t][1]);
        u1.h[1] = cvt2h(o1a[t][2], o1a[t][3]);
        _Float16* orow = Ob + ((size_t)b * S_ + q0 + t * 16 + col) * E_ + h * DH_;
        *reinterpret_cast<uint2*>(orow + quad * 4)      = u0.u;
        *reinterpret_cast<uint2*>(orow + 16 + quad * 4) = u1.u;
        if (quad == 0) lp[q0 + t * 16 + col] = la[t][0];
    }
}

// ---------------------------------------------------------------------------
// Kernel 3: output projection. R9: split-K4 — 8 waves = 2 n-waves x 4
// k-groups (n-tile 128, grid (256,6)). Per-wave dependent k-chain 12 -> 6
// phases; resident TLP 24 -> 32 waves/CU (1536 blocks, 4/CU cap). kg=1..3
// deposit f32 partials in padded LDS (<=2-way banked = free), kg=0 sums +
// bias + store. Per-wave register set identical to the spill-free R6 config.
// grid = (M/16, 768/128), block = 512.
// ---------------------------------------------------------------------------
template <int PARTS>
__global__ __launch_bounds__(512, 4) void proj_kernel(
    const _Float16* __restrict__ Opart,       // [PARTS][4096][768] fp16
    const float* __restrict__ lpart,          // [PARTS][B*H][S]
    const _Float16* __restrict__ Wob,         // [768][768] fp16
    const float* __restrict__ bo,             // [768] fp32
    float* __restrict__ out)                  // [4096][768] fp32
{
    __shared__ float lds[3 * 128 * 20];       // [kg-1][n_local 128][m 16 pad 20]

    const int wave = threadIdx.x >> 6;        // 0..7
    const int lane = threadIdx.x & 63;
    const int col  = lane & 15;
    const int quad = lane >> 4;
    const int kg   = wave >> 1;               // 0..3: k-group
    const int wn   = wave & 1;                // n-column
    const int m0   = blockIdx.x * 16;
    const int n0   = blockIdx.y * 128 + wn * 64;

    const int m = m0 + col;
    const int b = m / S_;
    const int s = m - b * S_;
    const float* lpb = lpart + (size_t)(b * H_) * S_ + s;
    const size_t BHS = (size_t)B_ * H_ * S_;
    const size_t BSE = (size_t)B_ * S_ * E_;

    union UA { uint4 u; half2v h[4]; half8 v; };

    f32x4 acc[4] = {{0.f,0.f,0.f,0.f},{0.f,0.f,0.f,0.f},
                    {0.f,0.f,0.f,0.f},{0.f,0.f,0.f,0.f}};

    float lA[PARTS]; UA oA[PARTS]; UA wA[4];
    float lB[PARTS]; UA oB[PARTS]; UA wB[4];

    auto load_a = [&](int k0) {
        const int h = k0 >> 5;
        const size_t aofs = (size_t)m * E_ + k0 + quad * 8;
#pragma unroll
        for (int pp = 0; pp < PARTS; ++pp) {
            lA[pp] = lpb[(size_t)pp * BHS + (size_t)h * S_];
            oA[pp].u = *reinterpret_cast<const uint4*>(
                Opart + (size_t)pp * BSE + aofs);
        }
#pragma unroll
        for (int j = 0; j < 4; ++j)
            wA[j].u = *reinterpret_cast<const uint4*>(
                Wob + (size_t)(n0 + j * 16 + col) * E_ + k0 + quad * 8);
    };
    auto load_b = [&](int k0) {
        const int h = k0 >> 5;
        const size_t aofs = (size_t)m * E_ + k0 + quad * 8;
#pragma unroll
        for (int pp = 0; pp < PARTS; ++pp) {
            lB[pp] = lpb[(size_t)pp * BHS + (size_t)h * S_];
            oB[pp].u = *reinterpret_cast<const uint4*>(
                Opart + (size_t)pp * BSE + aofs);
        }
#pragma unroll
        for (int j = 0; j < 4; ++j)
            wB[j].u = *reinterpret_cast<const uint4*>(
                Wob + (size_t)(n0 + j * 16 + col) * E_ + k0 + quad * 8);
    };
    auto comp_a = [&]() {
        float l = 0.f;
#pragma unroll
        for (int pp = 0; pp < PARTS; ++pp) l += lA[pp];
        const float linv = __builtin_amdgcn_rcpf(l);
        const half2v lv = cvt2h(linv, linv);
        UA ua = oA[0];
#pragma unroll
        for (int pp = 1; pp < PARTS; ++pp)
#pragma unroll
            for (int i = 0; i < 4; ++i) ua.h[i] += oA[pp].h[i];
#pragma unroll
        for (int i = 0; i < 4; ++i) ua.h[i] *= lv;
#pragma unroll
        for (int j = 0; j < 4; ++j)
            acc[j] = __builtin_amdgcn_mfma_f32_16x16x32_f16(ua.v, wA[j].v, acc[j], 0, 0, 0);
    };
    auto comp_b = [&]() {
        float l = 0.f;
#pragma unroll
        for (int pp = 0; pp < PARTS; ++pp) l += lB[pp];
        const float linv = __builtin_amdgcn_rcpf(l);
        const half2v lv = cvt2h(linv, linv);
        UA ua = oB[0];
#pragma unroll
        for (int pp = 1; pp < PARTS; ++pp)
#pragma unroll
            for (int i = 0; i < 4; ++i) ua.h[i] += oB[pp].h[i];
#pragma unroll
        for (int i = 0; i < 4; ++i) ua.h[i] *= lv;
#pragma unroll
        for (int j = 0; j < 4; ++j)
            acc[j] = __builtin_amdgcn_mfma_f32_16x16x32_f16(ua.v, wB[j].v, acc[j], 0, 0, 0);
    };

    const int kbeg = kg * (E_ / 4);           // 0 / 192 / 384 / 576
    const int kend = kbeg + E_ / 4;           // 6 phases of 32
    load_a(kbeg);
    for (int k0 = kbeg; k0 < kend; k0 += 64) {
        load_b(k0 + 32);
        comp_a();
        if (k0 + 64 < kend) load_a(k0 + 64);
        comp_b();
    }

    // split-K combine via LDS (pad 20 breaks the 16-float power-of-2 stride)
    if (kg > 0) {
#pragma unroll
        for (int j = 0; j < 4; ++j) {
            float* lp_ = &lds[(((kg - 1) * 128 + wn * 64 + j * 16 + col) * 20) + quad * 4];
#pragma unroll
            for (int r = 0; r < 4; ++r) lp_[r] = acc[j][r];
        }
    }
    __syncthreads();
    if (kg == 0) {
#pragma unroll
        for (int j = 0; j < 4; ++j) {
            const int row = wn * 64 + j * 16 + col;
            const float* p1 = &lds[((0 * 128 + row) * 20) + quad * 4];
            const float* p2 = &lds[((1 * 128 + row) * 20) + quad * 4];
            const float* p3 = &lds[((2 * 128 + row) * 20) + quad * 4];
            const int n = n0 + j * 16 + col;
            const float bias = bo[n];
#pragma unroll
            for (int r = 0; r < 4; ++r) {
                const int mm = m0 + quad * 4 + r;
                out[(size_t)mm * E_ + n] = acc[j][r] + p1[r] + p2[r] + p3[r] + bias;
            }
        }
    }
}

// ---------------------------------------------------------------------------
extern "C" void kernel_launch(void* const* d_in, const int* in_sizes, int n_in,
                              void* d_out, int out_size, void* d_ws, size_t ws_size,
                              hipStream_t stream)
{
    const float* emb = (const float*)d_in[0];
    const int*   msk = (const int*)d_in[1];
    const float* Wq  = (const float*)d_in[2];
    const float* Wk  = (const float*)d_in[3];
    const float* Wv  = (const float*)d_in[4];
    const float* Wo  = (const float*)d_in[5];
    const float* bo  = (const float*)d_in[6];
    float* out = (float*)d_out;

    const size_t nqkv = (size_t)B_ * H_ * S_ * DH_;   // 3,145,728 (= B*S*E)
    char* p = (char*)d_ws;
    __hip_bfloat16* Q    = (__hip_bfloat16*)p;  p += nqkv * 2;
    __hip_bfloat16* Kp   = (__hip_bfloat16*)p;  p += nqkv * 2;
    _Float16*      Vt    = (_Float16*)p;        p += nqkv * 2;
    unsigned int*  mbits = (unsigned int*)p;    p += (size_t)B_ * S_ * SW_ * 4;
    _Float16*      Wob   = (_Float16*)p;        p += (size_t)E_ * E_ * 2;
    _Float16*      Op    = (_Float16*)p;                      // [parts][B][S][E]
    const size_t base = (size_t)(p - (char*)d_ws);

    // parts = 2 (R4 post-mortem: 4 costs proj more than it gains attn)
    const size_t per_part = (size_t)nqkv * 2 + (size_t)B_ * H_ * S_ * 4;
    int parts = 1;
    if (ws_size >= base + 2 * per_part) parts = 2;
    float* lpart = (float*)(Op + (size_t)parts * nqkv);

    prep_qkv_kernel<<<NB_QKV + NB_MSK4 + NB_WO, 256, 0, stream>>>(
        emb, msk, Wo, Wq, Wk, Wv, Q, Kp, Vt, mbits, Wob);
    attn_kernel<<<1536 * parts, 64, 0, stream>>>(
        Q, Kp, Vt, mbits, Op, lpart, parts);
    if (parts == 2)
        proj_kernel<2><<<dim3((B_ * S_) / 16, E_ / 128), 512, 0, stream>>>(
            Op, lpart, Wob, bo, out);
    else
        proj_kernel<1><<<dim3((B_ * S_) / 16, E_ / 128), 512, 0, stream>>>(
            Op, lpart, Wob, bo, out);
}